// Round 3
// baseline (5308.116 us; speedup 1.0000x reference)
//
#include <hip/hip_runtime.h>
#include <hip/hip_fp16.h>

#define N 8192
#define DK 256
#define LOG2E 1.4426950408889634f
#define LN2   0.6931471805599453f
#define ZS    2.5f            // int8 dequant scale (Zl = q * ZS)
#define QS    1.1541560327f   // 2*log2e / ZS  (fp32 acc -> q units)
// log2(8192) = 13 exactly; (loga+logb) in log2 units = -26

typedef unsigned short u16;
typedef u16   ushort8 __attribute__((ext_vector_type(8)));
typedef __bf16 bf16x8 __attribute__((ext_vector_type(8)));
typedef float  f32x4  __attribute__((ext_vector_type(4)));

__device__ __forceinline__ u16 f2bf(float f){
  unsigned u = __builtin_bit_cast(unsigned, f);
  return (u16)((u + 0x7fffu + ((u >> 16) & 1u)) >> 16);   // RNE fp32->bf16
}
__device__ __forceinline__ float ex2(float x){            // v_exp_f32 = 2^x
  float r; asm("v_exp_f32 %0, %1" : "=v"(r) : "v"(x)); return r;
}
__device__ __forceinline__ float lg2(float x){            // v_log_f32 = log2(x)
  float r; asm("v_log_f32 %0, %1" : "=v"(r) : "v"(x)); return r;
}
// signed byte k of dword -> float
__device__ __forceinline__ float b2f(unsigned u, int k){
  if (k == 3) return (float)((int)u >> 24);
  return (float)(int)(signed char)((u >> (8 * k)) & 255u);
}

// ---------------------------------------------------------------------------
// prep: row sum-of-squares + bf16 copies + init GtL = -y2*log2e (g0=0)
// + zero the gpass completion counters (must be re-zeroed every call).
// ---------------------------------------------------------------------------
__global__ __launch_bounds__(256) void prep_k(const float* __restrict__ x, const float* __restrict__ y,
                                              u16* __restrict__ xb, u16* __restrict__ yb,
                                              float* __restrict__ x2, float* __restrict__ y2,
                                              float* __restrict__ gt, int* __restrict__ cnt){
  if (blockIdx.x == 0){
    for (int c = threadIdx.x; c < 400; c += 256) cnt[c] = 0;
  }
  const int w = threadIdx.x >> 6, l = threadIdx.x & 63;
  const int r = blockIdx.x * 4 + w;         // 0..16383
  const bool isx = r < N;
  const int rr = isx ? r : r - N;
  const float* src = (isx ? x : y) + (size_t)rr * DK;
  float4 v = *(const float4*)(src + l * 4);
  ushort4 bv;
  bv.x = f2bf(v.x); bv.y = f2bf(v.y); bv.z = f2bf(v.z); bv.w = f2bf(v.w);
  *(ushort4*)((isx ? xb : yb) + (size_t)rr * DK + l * 4) = bv;
  float p = v.x*v.x + v.y*v.y + v.z*v.z + v.w*v.w;
  #pragma unroll
  for (int off = 32; off > 0; off >>= 1) p += __shfl_down(p, off);
  if (l == 0){
    if (isx) x2[rr] = p;
    else { y2[rr] = p; gt[rr] = -p * LOG2E; }
  }
}

// ---------------------------------------------------------------------------
// gemm: z = xb * yb^T (bf16 MFMA). Quantize Zl = 2*log2e*z to int8 (scale ZS),
// stage tile in LDS, store coalesced dwordx4.
// ---------------------------------------------------------------------------
__global__ __launch_bounds__(256) void gemm_k(const u16* __restrict__ xb, const u16* __restrict__ yb,
                                              char* __restrict__ zq){
  __shared__ __align__(16) u16 As[128 * 72];
  __shared__ __align__(16) u16 Bs[128 * 72];
  const int t = threadIdx.x;
  const int w = t >> 6, l = t & 63;
  const int wm = w >> 1, wn = w & 1;
  const int brow = blockIdx.y * 128, bcol = blockIdx.x * 128;
  const int tr = t >> 3, tc = t & 7;
  f32x4 acc[4][4] = {};
  for (int ks = 0; ks < 4; ++ks){
    #pragma unroll
    for (int rr = 0; rr < 4; ++rr){
      const int row = tr + rr * 32;
      *(ushort8*)&As[row * 72 + tc * 8] = *(const ushort8*)&xb[(size_t)(brow + row) * DK + ks * 64 + tc * 8];
      *(ushort8*)&Bs[row * 72 + tc * 8] = *(const ushort8*)&yb[(size_t)(bcol + row) * DK + ks * 64 + tc * 8];
    }
    __syncthreads();
    #pragma unroll
    for (int kk = 0; kk < 2; ++kk){
      bf16x8 av[4], bv[4];
      #pragma unroll
      for (int mi = 0; mi < 4; ++mi){
        const int ar = wm * 64 + mi * 16 + (l & 15);
        av[mi] = __builtin_bit_cast(bf16x8, *(const ushort8*)&As[ar * 72 + kk * 32 + (l >> 4) * 8]);
      }
      #pragma unroll
      for (int ni = 0; ni < 4; ++ni){
        const int br = wn * 64 + ni * 16 + (l & 15);
        bv[ni] = __builtin_bit_cast(bf16x8, *(const ushort8*)&Bs[br * 72 + kk * 32 + (l >> 4) * 8]);
      }
      #pragma unroll
      for (int mi = 0; mi < 4; ++mi)
        #pragma unroll
        for (int ni = 0; ni < 4; ++ni)
          acc[mi][ni] = __builtin_amdgcn_mfma_f32_16x16x32_bf16(av[mi], bv[ni], acc[mi][ni], 0, 0, 0);
    }
    __syncthreads();
  }
  // quantize into LDS (reuse As as 128x128 int8 tile)
  char* Cs = (char*)As;
  #pragma unroll
  for (int mi = 0; mi < 4; ++mi){
    const int rowb = wm * 64 + mi * 16 + (l >> 4) * 4;
    #pragma unroll
    for (int ni = 0; ni < 4; ++ni){
      const int col = wn * 64 + ni * 16 + (l & 15);
      #pragma unroll
      for (int rr = 0; rr < 4; ++rr){
        float q = fminf(fmaxf(acc[mi][ni][rr] * QS, -127.f), 127.f);
        Cs[(rowb + rr) * 128 + col] = (char)(int)__builtin_rintf(q);
      }
    }
  }
  __syncthreads();
  const int trow0 = t >> 3, kseg = t & 7;
  #pragma unroll
  for (int ii = 0; ii < 4; ++ii){
    const int row = trow0 + ii * 32;
    int4 v = *(const int4*)(Cs + row * 128 + kseg * 16);
    *(int4*)(zq + (size_t)(brow + row) * N + bcol + kseg * 16) = v;
  }
}

// ---------------------------------------------------------------------------
// fpass: per row i, online log2-LSE_j(GtL_j + ZS*q_ij). One wave per row.
// 16 B z per lane per iter, depth-2 prefetch, group-of-16 max.
// MODE 0: FtL[i] = 13 - lse2
// MODE 1: r_i = 2^(FtL_i + lse2 - 26); contrib = (FtL*ln2 + x2)*r
// ---------------------------------------------------------------------------
template<int MODE>
__global__ __launch_bounds__(256) void fpass_k(const char* __restrict__ zq,
                                               const float* __restrict__ gt,
                                               float* ft,
                                               const float* __restrict__ x2,
                                               float* __restrict__ contrib){
  const int w = threadIdx.x >> 6, l = threadIdx.x & 63;
  const int i = blockIdx.x * 4 + w;
  const char* zr = zq + (size_t)i * N + l * 16;
  float m = -1e30f, s = 0.f;
  uint4 zA = *(const uint4*)(zr);
  #pragma unroll
  for (int it = 0; it < 8; ++it){
    uint4 zB = {};
    if (it < 7) zB = *(const uint4*)(zr + (it + 1) * 1024);
    const float* gp = gt + it * 1024 + l * 16;
    const float4 g0 = *(const float4*)(gp);
    const float4 g1 = *(const float4*)(gp + 4);
    const float4 g2 = *(const float4*)(gp + 8);
    const float4 g3 = *(const float4*)(gp + 12);
    float tt[16];
    tt[0]  = __builtin_fmaf(b2f(zA.x,0), ZS, g0.x);
    tt[1]  = __builtin_fmaf(b2f(zA.x,1), ZS, g0.y);
    tt[2]  = __builtin_fmaf(b2f(zA.x,2), ZS, g0.z);
    tt[3]  = __builtin_fmaf(b2f(zA.x,3), ZS, g0.w);
    tt[4]  = __builtin_fmaf(b2f(zA.y,0), ZS, g1.x);
    tt[5]  = __builtin_fmaf(b2f(zA.y,1), ZS, g1.y);
    tt[6]  = __builtin_fmaf(b2f(zA.y,2), ZS, g1.z);
    tt[7]  = __builtin_fmaf(b2f(zA.y,3), ZS, g1.w);
    tt[8]  = __builtin_fmaf(b2f(zA.z,0), ZS, g2.x);
    tt[9]  = __builtin_fmaf(b2f(zA.z,1), ZS, g2.y);
    tt[10] = __builtin_fmaf(b2f(zA.z,2), ZS, g2.z);
    tt[11] = __builtin_fmaf(b2f(zA.z,3), ZS, g2.w);
    tt[12] = __builtin_fmaf(b2f(zA.w,0), ZS, g3.x);
    tt[13] = __builtin_fmaf(b2f(zA.w,1), ZS, g3.y);
    tt[14] = __builtin_fmaf(b2f(zA.w,2), ZS, g3.z);
    tt[15] = __builtin_fmaf(b2f(zA.w,3), ZS, g3.w);
    // max tree over 16 + running m (clang fuses fmax pairs to v_max3)
    float a0 = fmaxf(tt[0], tt[1]),  a1 = fmaxf(tt[2], tt[3]);
    float a2 = fmaxf(tt[4], tt[5]),  a3 = fmaxf(tt[6], tt[7]);
    float a4 = fmaxf(tt[8], tt[9]),  a5 = fmaxf(tt[10], tt[11]);
    float a6 = fmaxf(tt[12], tt[13]), a7 = fmaxf(tt[14], tt[15]);
    float b0 = fmaxf(a0, a1), b1 = fmaxf(a2, a3), b2 = fmaxf(a4, a5), b3 = fmaxf(a6, a7);
    float nm = fmaxf(fmaxf(fmaxf(b0, b1), fmaxf(b2, b3)), m);
    float s0 = ex2(tt[0] - nm) + ex2(tt[1] - nm) + ex2(tt[2] - nm) + ex2(tt[3] - nm)
             + ex2(tt[4] - nm) + ex2(tt[5] - nm) + ex2(tt[6] - nm) + ex2(tt[7] - nm);
    float s1 = ex2(tt[8] - nm) + ex2(tt[9] - nm) + ex2(tt[10] - nm) + ex2(tt[11] - nm)
             + ex2(tt[12] - nm) + ex2(tt[13] - nm) + ex2(tt[14] - nm) + ex2(tt[15] - nm);
    s = __builtin_fmaf(s, ex2(m - nm), s0 + s1);
    m = nm;
    zA = zB;
  }
  #pragma unroll
  for (int off = 32; off > 0; off >>= 1){
    float om = __shfl_down(m, off);
    float os = __shfl_down(s, off);
    float nm = fmaxf(m, om);
    s = __builtin_fmaf(s, ex2(m - nm), os * ex2(om - nm));
    m = nm;
  }
  if (l == 0){
    float lse2 = m + lg2(s);
    if (MODE == 0){
      ft[i] = 13.0f - lse2;
    } else {
      float fti = ft[i];
      float r = ex2(fti + lse2 - 26.0f);
      contrib[i] = (fti * LN2 + x2[i]) * r;
    }
  }
}

// ---------------------------------------------------------------------------
// gpass: column log2-LSE_i(FtL_i + ZS*q_ij), 4 cols/thread, 128 rows/block,
// grid (8,64). Last block per column-chunk merges the 64 partials -> gt.
// ---------------------------------------------------------------------------
__global__ __launch_bounds__(256) void gpass_k(const char* __restrict__ zq,
                                               const float* __restrict__ ft,
                                               float* __restrict__ pm,
                                               float* __restrict__ ps,
                                               float* __restrict__ gt,
                                               int* __restrict__ cnt){
  const int c0 = blockIdx.x * 1024 + threadIdx.x * 4;
  const int r0base = blockIdx.y * 128;
  float m[4], s[4];
  #pragma unroll
  for (int e = 0; e < 4; ++e){ m[e] = -1e30f; s[e] = 0.f; }
  for (int rg = 0; rg < 16; ++rg){
    const int r0 = r0base + rg * 8;
    float t[8][4];
    #pragma unroll
    for (int r = 0; r < 8; ++r){
      const float fv = ft[r0 + r];           // block-uniform -> scalar load
      unsigned u = *(const unsigned*)(zq + (size_t)(r0 + r) * N + c0);
      t[r][0] = __builtin_fmaf(b2f(u,0), ZS, fv);
      t[r][1] = __builtin_fmaf(b2f(u,1), ZS, fv);
      t[r][2] = __builtin_fmaf(b2f(u,2), ZS, fv);
      t[r][3] = __builtin_fmaf(b2f(u,3), ZS, fv);
    }
    #pragma unroll
    for (int e = 0; e < 4; ++e){
      float nm = fmaxf(fmaxf(fmaxf(t[0][e], t[1][e]), fmaxf(t[2][e], t[3][e])),
                       fmaxf(fmaxf(t[4][e], t[5][e]), fmaxf(t[6][e], t[7][e])));
      nm = fmaxf(nm, m[e]);
      float sum = ex2(t[0][e] - nm) + ex2(t[1][e] - nm) + ex2(t[2][e] - nm) + ex2(t[3][e] - nm)
                + ex2(t[4][e] - nm) + ex2(t[5][e] - nm) + ex2(t[6][e] - nm) + ex2(t[7][e] - nm);
      s[e] = __builtin_fmaf(s[e], ex2(m[e] - nm), sum);
      m[e] = nm;
    }
  }
  const size_t pb = (size_t)blockIdx.y * N + c0;
  *(float4*)(pm + pb) = make_float4(m[0], m[1], m[2], m[3]);
  *(float4*)(ps + pb) = make_float4(s[0], s[1], s[2], s[3]);
  __threadfence();
  __shared__ int lastdone;
  if (threadIdx.x == 0) lastdone = (atomicAdd(cnt + blockIdx.x, 1) == 63) ? 1 : 0;
  __syncthreads();
  if (!lastdone) return;
  __threadfence();
  float mm[4], ss[4];
  #pragma unroll
  for (int e = 0; e < 4; ++e){ mm[e] = -1e30f; ss[e] = 0.f; }
  for (int ch = 0; ch < 64; ++ch){
    const float4 om = *(const float4*)(pm + (size_t)ch * N + c0);
    const float4 os = *(const float4*)(ps + (size_t)ch * N + c0);
    const float omv[4] = {om.x, om.y, om.z, om.w};
    const float osv[4] = {os.x, os.y, os.z, os.w};
    #pragma unroll
    for (int e = 0; e < 4; ++e){
      float nm = fmaxf(mm[e], omv[e]);
      ss[e] = __builtin_fmaf(ss[e], ex2(mm[e] - nm), osv[e] * ex2(omv[e] - nm));
      mm[e] = nm;
    }
  }
  float4 gout;
  gout.x = 13.0f - (mm[0] + lg2(ss[0]));
  gout.y = 13.0f - (mm[1] + lg2(ss[1]));
  gout.z = 13.0f - (mm[2] + lg2(ss[2]));
  gout.w = 13.0f - (mm[3] + lg2(ss[3]));
  *(float4*)(gt + c0) = gout;
}

// ---------------------------------------------------------------------------
// finish: value = sum(contrib) + mean_j(GtL_j*ln2 + y2_j); out = sqrt(value)
// ---------------------------------------------------------------------------
__global__ __launch_bounds__(256) void finish_k(const float* __restrict__ contrib,
                                                const float* __restrict__ gt,
                                                const float* __restrict__ y2,
                                                float* __restrict__ out){
  __shared__ float s1[256], s2[256];
  const int t = threadIdx.x;
  float a = 0.f, b = 0.f;
  for (int j = t; j < N; j += 256){ a += contrib[j]; b += gt[j] * LN2 + y2[j]; }
  s1[t] = a; s2[t] = b; __syncthreads();
  for (int st = 128; st > 0; st >>= 1){
    if (t < st){ s1[t] += s1[t + st]; s2[t] += s2[t + st]; }
    __syncthreads();
  }
  if (t == 0) out[0] = sqrtf(s1[0] + s2[0] * (1.0f / (float)N));
}

// ---------------------------------------------------------------------------
extern "C" void kernel_launch(void* const* d_in, const int* in_sizes, int n_in,
                              void* d_out, int out_size, void* d_ws, size_t ws_size,
                              hipStream_t stream){
  const float* x = (const float*)d_in[0];
  const float* y = (const float*)d_in[1];
  float* out = (float*)d_out;
  char* ws = (char*)d_ws;

  // workspace layout (bytes)
  char*  zq      = (char*) (ws);                 // int8 z, 64 MiB
  u16*   xb      = (u16*)  (ws + 67108864);      // bf16 x, 4 MiB
  u16*   yb      = (u16*)  (ws + 71303168);      // bf16 y, 4 MiB
  float* x2      = (float*)(ws + 75497472);
  float* y2      = (float*)(ws + 75530240);
  float* ft      = (float*)(ws + 75563008);
  float* gt      = (float*)(ws + 75595776);
  float* contrib = (float*)(ws + 75628544);
  float* pm      = (float*)(ws + 75661312);      // 64*8192*4 = 2 MiB
  float* ps      = (float*)(ws + 77758464);      // 2 MiB
  int*   cnt     = (int*)  (ws + 79855616);      // 8*50 counters

  prep_k<<<4096, 256, 0, stream>>>(x, y, xb, yb, x2, y2, gt, cnt);
  gemm_k<<<dim3(64, 64), 256, 0, stream>>>(xb, yb, zq);
  for (int it = 0; it < 50; ++it){
    fpass_k<0><<<2048, 256, 0, stream>>>(zq, gt, ft, x2, contrib);
    gpass_k<<<dim3(8, 64), 256, 0, stream>>>(zq, ft, pm, ps, gt, cnt + it * 8);
  }
  fpass_k<1><<<2048, 256, 0, stream>>>(zq, gt, ft, x2, contrib);
  finish_k<<<1, 256, 0, stream>>>(contrib, gt, y2, out);
}

// Round 4
// 2029.873 us; speedup vs baseline: 2.6150x; 2.6150x over previous
//
#include <hip/hip_runtime.h>

#define N 8192
#define DK 256
#define LOG2E 1.4426950408889634f
#define LN2   0.6931471805599453f
#define ZS    2.5f            // int8 dequant scale (Zl = q * ZS)
#define QS    1.1541560327f   // 2*log2e / ZS  (fp32 acc -> q units)
#define BIAS  320.0f          // 128 * ZS ; duals stored shifted by -BIAS
// log2(8192) = 13 exactly; (loga+logb) in log2 units = -26

typedef unsigned short u16;
typedef u16   ushort8 __attribute__((ext_vector_type(8)));
typedef __bf16 bf16x8 __attribute__((ext_vector_type(8)));
typedef float  f32x4  __attribute__((ext_vector_type(4)));

__device__ __forceinline__ u16 f2bf(float f){
  unsigned u = __builtin_bit_cast(unsigned, f);
  return (u16)((u + 0x7fffu + ((u >> 16) & 1u)) >> 16);   // RNE fp32->bf16
}
__device__ __forceinline__ float ex2(float x){            // v_exp_f32 = 2^x
  float r; asm("v_exp_f32 %0, %1" : "=v"(r) : "v"(x)); return r;
}
__device__ __forceinline__ float lg2(float x){            // v_log_f32 = log2(x)
  float r; asm("v_log_f32 %0, %1" : "=v"(r) : "v"(x)); return r;
}
__device__ __forceinline__ float cub0(unsigned u){ float r; asm("v_cvt_f32_ubyte0 %0, %1":"=v"(r):"v"(u)); return r; }
__device__ __forceinline__ float cub1(unsigned u){ float r; asm("v_cvt_f32_ubyte1 %0, %1":"=v"(r):"v"(u)); return r; }
__device__ __forceinline__ float cub2(unsigned u){ float r; asm("v_cvt_f32_ubyte2 %0, %1":"=v"(r):"v"(u)); return r; }
__device__ __forceinline__ float cub3(unsigned u){ float r; asm("v_cvt_f32_ubyte3 %0, %1":"=v"(r):"v"(u)); return r; }

// ---------------------------------------------------------------------------
// prep: row sum-of-squares + bf16 copies + init gts = -y2*LOG2E - BIAS (g0=0)
// ---------------------------------------------------------------------------
__global__ __launch_bounds__(256) void prep_k(const float* __restrict__ x, const float* __restrict__ y,
                                              u16* __restrict__ xb, u16* __restrict__ yb,
                                              float* __restrict__ x2, float* __restrict__ y2,
                                              float* __restrict__ gts){
  const int w = threadIdx.x >> 6, l = threadIdx.x & 63;
  const int r = blockIdx.x * 4 + w;         // 0..16383
  const bool isx = r < N;
  const int rr = isx ? r : r - N;
  const float* src = (isx ? x : y) + (size_t)rr * DK;
  float4 v = *(const float4*)(src + l * 4);
  ushort4 bv;
  bv.x = f2bf(v.x); bv.y = f2bf(v.y); bv.z = f2bf(v.z); bv.w = f2bf(v.w);
  *(ushort4*)((isx ? xb : yb) + (size_t)rr * DK + l * 4) = bv;
  float p = v.x*v.x + v.y*v.y + v.z*v.z + v.w*v.w;
  #pragma unroll
  for (int off = 32; off > 0; off >>= 1) p += __shfl_down(p, off);
  if (l == 0){
    if (isx) x2[rr] = p;
    else { y2[rr] = p; gts[rr] = -p * LOG2E - BIAS; }
  }
}

// ---------------------------------------------------------------------------
// gemm: z = xb*yb^T (bf16 MFMA). Quantize Zl = 2*log2e*z to biased uint8,
// stage tile (row-major in Cs for zq; col-major stride-144 in Ct for zqT),
// store both coalesced dwordx4.
// ---------------------------------------------------------------------------
__global__ __launch_bounds__(256) void gemm_k(const u16* __restrict__ xb, const u16* __restrict__ yb,
                                              unsigned char* __restrict__ zq,
                                              unsigned char* __restrict__ zqT){
  __shared__ __align__(16) u16 As[128 * 72];
  __shared__ __align__(16) u16 Bs[128 * 72];
  const int t = threadIdx.x;
  const int w = t >> 6, l = t & 63;
  const int wm = w >> 1, wn = w & 1;
  const int brow = blockIdx.y * 128, bcol = blockIdx.x * 128;
  const int tr = t >> 3, tc = t & 7;
  f32x4 acc[4][4] = {};
  for (int ks = 0; ks < 4; ++ks){
    #pragma unroll
    for (int rr = 0; rr < 4; ++rr){
      const int row = tr + rr * 32;
      *(ushort8*)&As[row * 72 + tc * 8] = *(const ushort8*)&xb[(size_t)(brow + row) * DK + ks * 64 + tc * 8];
      *(ushort8*)&Bs[row * 72 + tc * 8] = *(const ushort8*)&yb[(size_t)(bcol + row) * DK + ks * 64 + tc * 8];
    }
    __syncthreads();
    #pragma unroll
    for (int kk = 0; kk < 2; ++kk){
      bf16x8 av[4], bv[4];
      #pragma unroll
      for (int mi = 0; mi < 4; ++mi){
        const int ar = wm * 64 + mi * 16 + (l & 15);
        av[mi] = __builtin_bit_cast(bf16x8, *(const ushort8*)&As[ar * 72 + kk * 32 + (l >> 4) * 8]);
      }
      #pragma unroll
      for (int ni = 0; ni < 4; ++ni){
        const int br = wn * 64 + ni * 16 + (l & 15);
        bv[ni] = __builtin_bit_cast(bf16x8, *(const ushort8*)&Bs[br * 72 + kk * 32 + (l >> 4) * 8]);
      }
      #pragma unroll
      for (int mi = 0; mi < 4; ++mi)
        #pragma unroll
        for (int ni = 0; ni < 4; ++ni)
          acc[mi][ni] = __builtin_amdgcn_mfma_f32_16x16x32_bf16(av[mi], bv[ni], acc[mi][ni], 0, 0, 0);
    }
    __syncthreads();
  }
  // quantize: Cs row-major [128][128]; Ct col-major [col][row] stride 144
  unsigned char* Cs = (unsigned char*)As;
  unsigned char* Ct = (unsigned char*)Bs;
  #pragma unroll
  for (int mi = 0; mi < 4; ++mi){
    const int rowb = wm * 64 + mi * 16 + (l >> 4) * 4;
    #pragma unroll
    for (int ni = 0; ni < 4; ++ni){
      const int col = wn * 64 + ni * 16 + (l & 15);
      unsigned pk = 0;
      #pragma unroll
      for (int rr = 0; rr < 4; ++rr){
        float q = fminf(fmaxf(acc[mi][ni][rr] * QS, -127.f), 127.f);
        unsigned b = (unsigned)((int)__builtin_rintf(q) + 128) & 255u;
        Cs[(rowb + rr) * 128 + col] = (unsigned char)b;
        pk |= b << (8 * rr);
      }
      *(unsigned*)(Ct + col * 144 + rowb) = pk;
    }
  }
  __syncthreads();
  const int trow0 = t >> 3, kseg = t & 7;
  #pragma unroll
  for (int ii = 0; ii < 4; ++ii){
    const int row = trow0 + ii * 32;
    int4 v = *(const int4*)(Cs + row * 128 + kseg * 16);
    *(int4*)(zq + (size_t)(brow + row) * N + bcol + kseg * 16) = v;
    int4 vt = *(const int4*)(Ct + row * 144 + kseg * 16);
    *(int4*)(zqT + (size_t)(bcol + row) * N + brow + kseg * 16) = vt;
  }
}

// ---------------------------------------------------------------------------
// sweep: per row i of z (N cols), online log2-LSE_j(din_j + ZS*ub_ij).
// Duals stored shifted by -BIAS; biased ubyte makes t exact:
//   t = ub*ZS + din = (q+128)*ZS + d_true - BIAS = q*ZS + d_true.
// One wave per row, 16 B/lane/iter, depth-2 prefetch, group-of-16 max.
// MODE 0: dout[i] = 13 - lse2 - BIAS     (used for BOTH f- and g-updates)
// MODE 1: r_i = 2^(fprev_true + lse2 - 26); contrib = (fprev_true*ln2 + x2)*r
// ---------------------------------------------------------------------------
template<int MODE>
__global__ __launch_bounds__(256) void sweep_k(const unsigned char* __restrict__ z,
                                               const float* __restrict__ din,
                                               float* __restrict__ dout,
                                               const float* __restrict__ fprev,
                                               const float* __restrict__ x2,
                                               float* __restrict__ contrib){
  const int w = threadIdx.x >> 6, l = threadIdx.x & 63;
  const int i = blockIdx.x * 4 + w;
  const unsigned char* zr = z + (size_t)i * N + l * 16;
  float m = -1e30f, s = 0.f;
  uint4 zA = *(const uint4*)(zr);
  #pragma unroll
  for (int it = 0; it < 8; ++it){
    uint4 zB = {};
    if (it < 7) zB = *(const uint4*)(zr + (it + 1) * 1024);
    const float* gp = din + it * 1024 + l * 16;
    const float4 g0 = *(const float4*)(gp);
    const float4 g1 = *(const float4*)(gp + 4);
    const float4 g2 = *(const float4*)(gp + 8);
    const float4 g3 = *(const float4*)(gp + 12);
    float tt[16];
    tt[0]  = __builtin_fmaf(cub0(zA.x), ZS, g0.x);
    tt[1]  = __builtin_fmaf(cub1(zA.x), ZS, g0.y);
    tt[2]  = __builtin_fmaf(cub2(zA.x), ZS, g0.z);
    tt[3]  = __builtin_fmaf(cub3(zA.x), ZS, g0.w);
    tt[4]  = __builtin_fmaf(cub0(zA.y), ZS, g1.x);
    tt[5]  = __builtin_fmaf(cub1(zA.y), ZS, g1.y);
    tt[6]  = __builtin_fmaf(cub2(zA.y), ZS, g1.z);
    tt[7]  = __builtin_fmaf(cub3(zA.y), ZS, g1.w);
    tt[8]  = __builtin_fmaf(cub0(zA.z), ZS, g2.x);
    tt[9]  = __builtin_fmaf(cub1(zA.z), ZS, g2.y);
    tt[10] = __builtin_fmaf(cub2(zA.z), ZS, g2.z);
    tt[11] = __builtin_fmaf(cub3(zA.z), ZS, g2.w);
    tt[12] = __builtin_fmaf(cub0(zA.w), ZS, g3.x);
    tt[13] = __builtin_fmaf(cub1(zA.w), ZS, g3.y);
    tt[14] = __builtin_fmaf(cub2(zA.w), ZS, g3.z);
    tt[15] = __builtin_fmaf(cub3(zA.w), ZS, g3.w);
    float a0 = fmaxf(tt[0], tt[1]),  a1 = fmaxf(tt[2], tt[3]);
    float a2 = fmaxf(tt[4], tt[5]),  a3 = fmaxf(tt[6], tt[7]);
    float a4 = fmaxf(tt[8], tt[9]),  a5 = fmaxf(tt[10], tt[11]);
    float a6 = fmaxf(tt[12], tt[13]), a7 = fmaxf(tt[14], tt[15]);
    float b0 = fmaxf(a0, a1), b1 = fmaxf(a2, a3), b2 = fmaxf(a4, a5), b3 = fmaxf(a6, a7);
    float nm = fmaxf(fmaxf(fmaxf(b0, b1), fmaxf(b2, b3)), m);
    float s0 = ex2(tt[0] - nm) + ex2(tt[1] - nm) + ex2(tt[2] - nm) + ex2(tt[3] - nm)
             + ex2(tt[4] - nm) + ex2(tt[5] - nm) + ex2(tt[6] - nm) + ex2(tt[7] - nm);
    float s1 = ex2(tt[8] - nm) + ex2(tt[9] - nm) + ex2(tt[10] - nm) + ex2(tt[11] - nm)
             + ex2(tt[12] - nm) + ex2(tt[13] - nm) + ex2(tt[14] - nm) + ex2(tt[15] - nm);
    s = __builtin_fmaf(s, ex2(m - nm), s0 + s1);
    m = nm;
    zA = zB;
  }
  #pragma unroll
  for (int off = 32; off > 0; off >>= 1){
    float om = __shfl_down(m, off);
    float os = __shfl_down(s, off);
    float nm = fmaxf(m, om);
    s = __builtin_fmaf(s, ex2(m - nm), os * ex2(om - nm));
    m = nm;
  }
  if (l == 0){
    float lse2 = m + lg2(s);          // true lse2 (shift cancels via bias)
    if (MODE == 0){
      dout[i] = 13.0f - lse2 - BIAS;
    } else {
      float fti = fprev[i] + BIAS;    // true FtL
      float r = ex2(fti + lse2 - 26.0f);
      contrib[i] = (fti * LN2 + x2[i]) * r;
    }
  }
}

// ---------------------------------------------------------------------------
// finish: value = sum(contrib) + mean_j((gts_j+BIAS)*ln2 + y2_j); out = sqrt
// ---------------------------------------------------------------------------
__global__ __launch_bounds__(256) void finish_k(const float* __restrict__ contrib,
                                                const float* __restrict__ gts,
                                                const float* __restrict__ y2,
                                                float* __restrict__ out){
  __shared__ float s1[256], s2[256];
  const int t = threadIdx.x;
  float a = 0.f, b = 0.f;
  for (int j = t; j < N; j += 256){ a += contrib[j]; b += (gts[j] + BIAS) * LN2 + y2[j]; }
  s1[t] = a; s2[t] = b; __syncthreads();
  for (int st = 128; st > 0; st >>= 1){
    if (t < st){ s1[t] += s1[t + st]; s2[t] += s2[t + st]; }
    __syncthreads();
  }
  if (t == 0) out[0] = sqrtf(s1[0] + s2[0] * (1.0f / (float)N));
}

// ---------------------------------------------------------------------------
extern "C" void kernel_launch(void* const* d_in, const int* in_sizes, int n_in,
                              void* d_out, int out_size, void* d_ws, size_t ws_size,
                              hipStream_t stream){
  const float* x = (const float*)d_in[0];
  const float* y = (const float*)d_in[1];
  float* out = (float*)d_out;
  char* ws = (char*)d_ws;

  // workspace layout (bytes)
  unsigned char* zq  = (unsigned char*)(ws);              // 64 MiB
  unsigned char* zqT = (unsigned char*)(ws + 67108864);   // 64 MiB
  u16*   xb      = (u16*)  (ws + 134217728);              // 4 MiB
  u16*   yb      = (u16*)  (ws + 138412032);              // 4 MiB
  float* x2      = (float*)(ws + 142606336);
  float* y2      = (float*)(ws + 142639104);
  float* fts     = (float*)(ws + 142671872);
  float* gts     = (float*)(ws + 142704640);
  float* contrib = (float*)(ws + 142737408);

  prep_k<<<4096, 256, 0, stream>>>(x, y, xb, yb, x2, y2, gts);
  gemm_k<<<dim3(64, 64), 256, 0, stream>>>(xb, yb, zq, zqT);
  for (int it = 0; it < 50; ++it){
    sweep_k<0><<<2048, 256, 0, stream>>>(zq,  gts, fts, nullptr, nullptr, nullptr);
    sweep_k<0><<<2048, 256, 0, stream>>>(zqT, fts, gts, nullptr, nullptr, nullptr);
  }
  sweep_k<1><<<2048, 256, 0, stream>>>(zq, gts, nullptr, fts, x2, contrib);
  finish_k<<<1, 256, 0, stream>>>(contrib, gts, y2, out);
}

// Round 5
// 1645.091 us; speedup vs baseline: 3.2266x; 1.2339x over previous
//
#include <hip/hip_runtime.h>

#define N 8192
#define DK 256
#define LOG2E 1.4426950408889634f
#define LN2   0.6931471805599453f
#define ZS    2.5f            // int8 dequant scale (Zl = q * ZS)
#define QS    1.1541560327f   // 2*log2e / ZS  (fp32 acc -> q units)
#define BIAS  320.0f          // 128 * ZS ; duals stored shifted by -BIAS
// log2(8192) = 13 exactly; (loga+logb) in log2 units = -26

typedef unsigned short u16;
typedef u16   ushort8 __attribute__((ext_vector_type(8)));
typedef __bf16 bf16x8 __attribute__((ext_vector_type(8)));
typedef float  f32x4  __attribute__((ext_vector_type(4)));

__device__ __forceinline__ u16 f2bf(float f){
  unsigned u = __builtin_bit_cast(unsigned, f);
  return (u16)((u + 0x7fffu + ((u >> 16) & 1u)) >> 16);   // RNE fp32->bf16
}
__device__ __forceinline__ float ex2(float x){            // v_exp_f32 = 2^x
  float r; asm("v_exp_f32 %0, %1" : "=v"(r) : "v"(x)); return r;
}
__device__ __forceinline__ float lg2(float x){            // v_log_f32 = log2(x)
  float r; asm("v_log_f32 %0, %1" : "=v"(r) : "v"(x)); return r;
}
__device__ __forceinline__ float cub0(unsigned u){ float r; asm("v_cvt_f32_ubyte0 %0, %1":"=v"(r):"v"(u)); return r; }
__device__ __forceinline__ float cub1(unsigned u){ float r; asm("v_cvt_f32_ubyte1 %0, %1":"=v"(r):"v"(u)); return r; }
__device__ __forceinline__ float cub2(unsigned u){ float r; asm("v_cvt_f32_ubyte2 %0, %1":"=v"(r):"v"(u)); return r; }
__device__ __forceinline__ float cub3(unsigned u){ float r; asm("v_cvt_f32_ubyte3 %0, %1":"=v"(r):"v"(u)); return r; }

// sum of 4 exp2 terms for one row: t_e = q_e*ZS + (g_e - M)
__device__ __forceinline__ float quad(unsigned u, float4 gv, float M){
  float t0 = __builtin_fmaf(cub0(u), ZS, gv.x - M);
  float t1 = __builtin_fmaf(cub1(u), ZS, gv.y - M);
  float t2 = __builtin_fmaf(cub2(u), ZS, gv.z - M);
  float t3 = __builtin_fmaf(cub3(u), ZS, gv.w - M);
  return (ex2(t0) + ex2(t1)) + (ex2(t2) + ex2(t3));
}

// ---------------------------------------------------------------------------
// prep: row sum-of-squares + bf16 copies + init gts = -y2*LOG2E - BIAS (g0=0)
// ---------------------------------------------------------------------------
__global__ __launch_bounds__(256) void prep_k(const float* __restrict__ x, const float* __restrict__ y,
                                              u16* __restrict__ xb, u16* __restrict__ yb,
                                              float* __restrict__ x2, float* __restrict__ y2,
                                              float* __restrict__ gts){
  const int w = threadIdx.x >> 6, l = threadIdx.x & 63;
  const int r = blockIdx.x * 4 + w;         // 0..16383
  const bool isx = r < N;
  const int rr = isx ? r : r - N;
  const float* src = (isx ? x : y) + (size_t)rr * DK;
  float4 v = *(const float4*)(src + l * 4);
  ushort4 bv;
  bv.x = f2bf(v.x); bv.y = f2bf(v.y); bv.z = f2bf(v.z); bv.w = f2bf(v.w);
  *(ushort4*)((isx ? xb : yb) + (size_t)rr * DK + l * 4) = bv;
  float p = v.x*v.x + v.y*v.y + v.z*v.z + v.w*v.w;
  #pragma unroll
  for (int off = 32; off > 0; off >>= 1) p += __shfl_down(p, off);
  if (l == 0){
    if (isx) x2[rr] = p;
    else { y2[rr] = p; gts[rr] = -p * LOG2E - BIAS; }
  }
}

// ---------------------------------------------------------------------------
// gemm: z = xb*yb^T (bf16 MFMA). Quantize Zl = 2*log2e*z to biased uint8,
// stage tiles in LDS, store zq and zqT coalesced dwordx4.
// ---------------------------------------------------------------------------
__global__ __launch_bounds__(256) void gemm_k(const u16* __restrict__ xb, const u16* __restrict__ yb,
                                              unsigned char* __restrict__ zq,
                                              unsigned char* __restrict__ zqT){
  __shared__ __align__(16) u16 As[128 * 72];
  __shared__ __align__(16) u16 Bs[128 * 72];
  const int t = threadIdx.x;
  const int w = t >> 6, l = t & 63;
  const int wm = w >> 1, wn = w & 1;
  const int brow = blockIdx.y * 128, bcol = blockIdx.x * 128;
  const int tr = t >> 3, tc = t & 7;
  f32x4 acc[4][4] = {};
  for (int ks = 0; ks < 4; ++ks){
    #pragma unroll
    for (int rr = 0; rr < 4; ++rr){
      const int row = tr + rr * 32;
      *(ushort8*)&As[row * 72 + tc * 8] = *(const ushort8*)&xb[(size_t)(brow + row) * DK + ks * 64 + tc * 8];
      *(ushort8*)&Bs[row * 72 + tc * 8] = *(const ushort8*)&yb[(size_t)(bcol + row) * DK + ks * 64 + tc * 8];
    }
    __syncthreads();
    #pragma unroll
    for (int kk = 0; kk < 2; ++kk){
      bf16x8 av[4], bv[4];
      #pragma unroll
      for (int mi = 0; mi < 4; ++mi){
        const int ar = wm * 64 + mi * 16 + (l & 15);
        av[mi] = __builtin_bit_cast(bf16x8, *(const ushort8*)&As[ar * 72 + kk * 32 + (l >> 4) * 8]);
      }
      #pragma unroll
      for (int ni = 0; ni < 4; ++ni){
        const int br = wn * 64 + ni * 16 + (l & 15);
        bv[ni] = __builtin_bit_cast(bf16x8, *(const ushort8*)&Bs[br * 72 + kk * 32 + (l >> 4) * 8]);
      }
      #pragma unroll
      for (int mi = 0; mi < 4; ++mi)
        #pragma unroll
        for (int ni = 0; ni < 4; ++ni)
          acc[mi][ni] = __builtin_amdgcn_mfma_f32_16x16x32_bf16(av[mi], bv[ni], acc[mi][ni], 0, 0, 0);
    }
    __syncthreads();
  }
  // quantize: Cs row-major [128][128]; Ct col-major [col][row] stride 144
  unsigned char* Cs = (unsigned char*)As;
  unsigned char* Ct = (unsigned char*)Bs;
  #pragma unroll
  for (int mi = 0; mi < 4; ++mi){
    const int rowb = wm * 64 + mi * 16 + (l >> 4) * 4;
    #pragma unroll
    for (int ni = 0; ni < 4; ++ni){
      const int col = wn * 64 + ni * 16 + (l & 15);
      unsigned pk = 0;
      #pragma unroll
      for (int rr = 0; rr < 4; ++rr){
        float q = fminf(fmaxf(acc[mi][ni][rr] * QS, -127.f), 127.f);
        unsigned b = (unsigned)((int)__builtin_rintf(q) + 128) & 255u;
        Cs[(rowb + rr) * 128 + col] = (unsigned char)b;
        pk |= b << (8 * rr);
      }
      *(unsigned*)(Ct + col * 144 + rowb) = pk;
    }
  }
  __syncthreads();
  const int trow0 = t >> 3, kseg = t & 7;
  #pragma unroll
  for (int ii = 0; ii < 4; ++ii){
    const int row = trow0 + ii * 32;
    int4 v = *(const int4*)(Cs + row * 128 + kseg * 16);
    *(int4*)(zq + (size_t)(brow + row) * N + bcol + kseg * 16) = v;
    int4 vt = *(const int4*)(Ct + row * 144 + kseg * 16);
    *(int4*)(zqT + (size_t)(bcol + row) * N + brow + kseg * 16) = vt;
  }
}

// ---------------------------------------------------------------------------
// sweept: bootstrap sweep with full online-max tracking (1 row/wave).
// Also stores pmax_out[i] = lse2 for the premax (fast) kernel.
// ---------------------------------------------------------------------------
__global__ __launch_bounds__(256) void sweept_k(const unsigned char* __restrict__ z,
                                                const float* __restrict__ din,
                                                float* __restrict__ dout,
                                                float* __restrict__ pmax_out){
  const int w = threadIdx.x >> 6, l = threadIdx.x & 63;
  const int i = blockIdx.x * 4 + w;
  const unsigned char* zr = z + (size_t)i * N + l * 16;
  float m = -1e30f, s = 0.f;
  uint4 zA = *(const uint4*)(zr);
  #pragma unroll
  for (int it = 0; it < 8; ++it){
    uint4 zB = zA;
    if (it < 7) zB = *(const uint4*)(zr + (it + 1) * 1024);
    const float* gp = din + it * 1024 + l * 16;
    const float4 g0 = *(const float4*)(gp);
    const float4 g1 = *(const float4*)(gp + 4);
    const float4 g2 = *(const float4*)(gp + 8);
    const float4 g3 = *(const float4*)(gp + 12);
    float tt[16];
    tt[0]  = __builtin_fmaf(cub0(zA.x), ZS, g0.x);
    tt[1]  = __builtin_fmaf(cub1(zA.x), ZS, g0.y);
    tt[2]  = __builtin_fmaf(cub2(zA.x), ZS, g0.z);
    tt[3]  = __builtin_fmaf(cub3(zA.x), ZS, g0.w);
    tt[4]  = __builtin_fmaf(cub0(zA.y), ZS, g1.x);
    tt[5]  = __builtin_fmaf(cub1(zA.y), ZS, g1.y);
    tt[6]  = __builtin_fmaf(cub2(zA.y), ZS, g1.z);
    tt[7]  = __builtin_fmaf(cub3(zA.y), ZS, g1.w);
    tt[8]  = __builtin_fmaf(cub0(zA.z), ZS, g2.x);
    tt[9]  = __builtin_fmaf(cub1(zA.z), ZS, g2.y);
    tt[10] = __builtin_fmaf(cub2(zA.z), ZS, g2.z);
    tt[11] = __builtin_fmaf(cub3(zA.z), ZS, g2.w);
    tt[12] = __builtin_fmaf(cub0(zA.w), ZS, g3.x);
    tt[13] = __builtin_fmaf(cub1(zA.w), ZS, g3.y);
    tt[14] = __builtin_fmaf(cub2(zA.w), ZS, g3.z);
    tt[15] = __builtin_fmaf(cub3(zA.w), ZS, g3.w);
    float a0 = fmaxf(tt[0], tt[1]),  a1 = fmaxf(tt[2], tt[3]);
    float a2 = fmaxf(tt[4], tt[5]),  a3 = fmaxf(tt[6], tt[7]);
    float a4 = fmaxf(tt[8], tt[9]),  a5 = fmaxf(tt[10], tt[11]);
    float a6 = fmaxf(tt[12], tt[13]), a7 = fmaxf(tt[14], tt[15]);
    float b0 = fmaxf(a0, a1), b1 = fmaxf(a2, a3), b2 = fmaxf(a4, a5), b3 = fmaxf(a6, a7);
    float nm = fmaxf(fmaxf(fmaxf(b0, b1), fmaxf(b2, b3)), m);
    float s0 = ex2(tt[0] - nm) + ex2(tt[1] - nm) + ex2(tt[2] - nm) + ex2(tt[3] - nm)
             + ex2(tt[4] - nm) + ex2(tt[5] - nm) + ex2(tt[6] - nm) + ex2(tt[7] - nm);
    float s1 = ex2(tt[8] - nm) + ex2(tt[9] - nm) + ex2(tt[10] - nm) + ex2(tt[11] - nm)
             + ex2(tt[12] - nm) + ex2(tt[13] - nm) + ex2(tt[14] - nm) + ex2(tt[15] - nm);
    s = __builtin_fmaf(s, ex2(m - nm), s0 + s1);
    m = nm;
    zA = zB;
  }
  #pragma unroll
  for (int off = 32; off > 0; off >>= 1){
    float om = __shfl_down(m, off);
    float os = __shfl_down(s, off);
    float nm = fmaxf(m, om);
    s = __builtin_fmaf(s, ex2(m - nm), os * ex2(om - nm));
    m = nm;
  }
  if (l == 0){
    float lse2 = m + lg2(s);          // true lse2 (bias cancels)
    dout[i] = 13.0f - lse2 - BIAS;
    pmax_out[i] = lse2;
  }
}

// ---------------------------------------------------------------------------
// sweepf: premax sweep. 2 rows per wave, half the columns; s = sum 2^(t - M)
// with M = previous sweep's lse for this row (exact math, no max tracking).
// Block = 4 waves covers 4 rows x full width; LDS merge of the 2 halves.
// MODE 0: dout[i] = 13 - lse - BIAS ; pmax_out[i] = lse
// MODE 1: r_i = 2^(fprev_true + lse - 26); contrib = (fprev_true*ln2 + x2)*r
// ---------------------------------------------------------------------------
template<int MODE>
__global__ __launch_bounds__(256, 8) void sweepf_k(const unsigned char* __restrict__ z,
                                                   const float* __restrict__ din,
                                                   float* __restrict__ dout,
                                                   const float* __restrict__ pmax_in,
                                                   float* __restrict__ pmax_out,
                                                   const float* __restrict__ fprev,
                                                   const float* __restrict__ x2,
                                                   float* __restrict__ contrib){
  const int w = threadIdx.x >> 6, l = threadIdx.x & 63;
  const int p = w & 1, h = w >> 1;
  const int r0 = blockIdx.x * 4;
  const int i0 = r0 + 2 * p, i1 = i0 + 1;
  const float M0 = pmax_in[i0], M1 = pmax_in[i1];
  const int cbase = h * 4096 + l * 16;
  const unsigned char* z0 = z + (size_t)i0 * N + cbase;
  const unsigned char* z1 = z + (size_t)i1 * N + cbase;
  float s0 = 0.f, s1 = 0.f;
  uint4 a0 = *(const uint4*)z0;
  uint4 a1 = *(const uint4*)z1;
  #pragma unroll
  for (int it = 0; it < 4; ++it){
    uint4 b0 = a0, b1 = a1;
    if (it < 3){
      b0 = *(const uint4*)(z0 + (it + 1) * 1024);
      b1 = *(const uint4*)(z1 + (it + 1) * 1024);
    }
    const float* gp = din + h * 4096 + it * 1024 + l * 16;
    const float4 g0 = *(const float4*)(gp);
    const float4 g1 = *(const float4*)(gp + 4);
    const float4 g2 = *(const float4*)(gp + 8);
    const float4 g3 = *(const float4*)(gp + 12);
    s0 += (quad(a0.x, g0, M0) + quad(a0.y, g1, M0))
        + (quad(a0.z, g2, M0) + quad(a0.w, g3, M0));
    s1 += (quad(a1.x, g0, M1) + quad(a1.y, g1, M1))
        + (quad(a1.z, g2, M1) + quad(a1.w, g3, M1));
    a0 = b0; a1 = b1;
  }
  #pragma unroll
  for (int off = 32; off > 0; off >>= 1){
    s0 += __shfl_down(s0, off);
    s1 += __shfl_down(s1, off);
  }
  __shared__ float sB[4][2];
  if (l == 0){ sB[2 * p + 0][h] = s0; sB[2 * p + 1][h] = s1; }
  __syncthreads();
  if (threadIdx.x < 4){
    const int row = r0 + threadIdx.x;
    float s = sB[threadIdx.x][0] + sB[threadIdx.x][1];
    float M = pmax_in[row];
    float lse = M + lg2(s);
    if (MODE == 0){
      dout[row] = 13.0f - lse - BIAS;
      pmax_out[row] = lse;
    } else {
      float fti = fprev[row] + BIAS;    // true FtL
      float r = ex2(fti + lse - 26.0f);
      contrib[row] = (fti * LN2 + x2[row]) * r;
    }
  }
}

// ---------------------------------------------------------------------------
// finish: value = sum(contrib) + mean_j((gts_j+BIAS)*ln2 + y2_j); out = sqrt
// ---------------------------------------------------------------------------
__global__ __launch_bounds__(256) void finish_k(const float* __restrict__ contrib,
                                                const float* __restrict__ gts,
                                                const float* __restrict__ y2,
                                                float* __restrict__ out){
  __shared__ float s1[256], s2[256];
  const int t = threadIdx.x;
  float a = 0.f, b = 0.f;
  for (int j = t; j < N; j += 256){ a += contrib[j]; b += (gts[j] + BIAS) * LN2 + y2[j]; }
  s1[t] = a; s2[t] = b; __syncthreads();
  for (int st = 128; st > 0; st >>= 1){
    if (t < st){ s1[t] += s1[t + st]; s2[t] += s2[t + st]; }
    __syncthreads();
  }
  if (t == 0) out[0] = sqrtf(s1[0] + s2[0] * (1.0f / (float)N));
}

// ---------------------------------------------------------------------------
extern "C" void kernel_launch(void* const* d_in, const int* in_sizes, int n_in,
                              void* d_out, int out_size, void* d_ws, size_t ws_size,
                              hipStream_t stream){
  const float* x = (const float*)d_in[0];
  const float* y = (const float*)d_in[1];
  float* out = (float*)d_out;
  char* ws = (char*)d_ws;

  // workspace layout (bytes)
  unsigned char* zq  = (unsigned char*)(ws);              // 64 MiB
  unsigned char* zqT = (unsigned char*)(ws + 67108864);   // 64 MiB
  u16*   xb      = (u16*)  (ws + 134217728);              // 4 MiB
  u16*   yb      = (u16*)  (ws + 138412032);              // 4 MiB
  float* x2      = (float*)(ws + 142606336);
  float* y2      = (float*)(ws + 142639104);
  float* fts     = (float*)(ws + 142671872);
  float* gts     = (float*)(ws + 142704640);
  float* contrib = (float*)(ws + 142737408);
  float* pmaxF   = (float*)(ws + 142770176);
  float* pmaxG   = (float*)(ws + 142802944);

  prep_k<<<4096, 256, 0, stream>>>(x, y, xb, yb, x2, y2, gts);
  gemm_k<<<dim3(64, 64), 256, 0, stream>>>(xb, yb, zq, zqT);
  // bootstrap: 3 iterations with full max tracking (also seeds premax)
  for (int it = 0; it < 3; ++it){
    sweept_k<<<2048, 256, 0, stream>>>(zq,  gts, fts, pmaxF);
    sweept_k<<<2048, 256, 0, stream>>>(zqT, fts, gts, pmaxG);
  }
  // fast premax iterations
  for (int it = 3; it < 50; ++it){
    sweepf_k<0><<<2048, 256, 0, stream>>>(zq,  gts, fts, pmaxF, pmaxF, nullptr, nullptr, nullptr);
    sweepf_k<0><<<2048, 256, 0, stream>>>(zqT, fts, gts, pmaxG, pmaxG, nullptr, nullptr, nullptr);
  }
  sweepf_k<1><<<2048, 256, 0, stream>>>(zq, gts, nullptr, pmaxF, nullptr, fts, x2, contrib);
  finish_k<<<1, 256, 0, stream>>>(contrib, gts, y2, out);
}

// Round 6
// 1642.078 us; speedup vs baseline: 3.2326x; 1.0018x over previous
//
#include <hip/hip_runtime.h>

#define N 8192
#define DK 256
#define LOG2E 1.4426950408889634f
#define LN2   0.6931471805599453f
#define ZS    2.5f            // int8 dequant scale (Zl = q * ZS)
#define QS    1.1541560327f   // 2*log2e / ZS  (fp32 acc -> q units)
#define BIAS  320.0f          // 128 * ZS ; duals stored shifted by -BIAS
// log2(8192) = 13 exactly; (loga+logb) in log2 units = -26

typedef unsigned short u16;
typedef u16   ushort8 __attribute__((ext_vector_type(8)));
typedef __bf16 bf16x8 __attribute__((ext_vector_type(8)));
typedef float  f32x4  __attribute__((ext_vector_type(4)));

__device__ __forceinline__ u16 f2bf(float f){
  unsigned u = __builtin_bit_cast(unsigned, f);
  return (u16)((u + 0x7fffu + ((u >> 16) & 1u)) >> 16);   // RNE fp32->bf16
}
__device__ __forceinline__ float ex2(float x){            // v_exp_f32 = 2^x
  float r; asm("v_exp_f32 %0, %1" : "=v"(r) : "v"(x)); return r;
}
__device__ __forceinline__ float lg2(float x){            // v_log_f32 = log2(x)
  float r; asm("v_log_f32 %0, %1" : "=v"(r) : "v"(x)); return r;
}
__device__ __forceinline__ float cub0(unsigned u){ float r; asm("v_cvt_f32_ubyte0 %0, %1":"=v"(r):"v"(u)); return r; }
__device__ __forceinline__ float cub1(unsigned u){ float r; asm("v_cvt_f32_ubyte1 %0, %1":"=v"(r):"v"(u)); return r; }
__device__ __forceinline__ float cub2(unsigned u){ float r; asm("v_cvt_f32_ubyte2 %0, %1":"=v"(r):"v"(u)); return r; }
__device__ __forceinline__ float cub3(unsigned u){ float r; asm("v_cvt_f32_ubyte3 %0, %1":"=v"(r):"v"(u)); return r; }

// sum of 4 exp2 terms for one row: t_e = q_e*ZS + (g_e - M)
__device__ __forceinline__ float quad(unsigned u, float4 gv, float M){
  float t0 = __builtin_fmaf(cub0(u), ZS, gv.x - M);
  float t1 = __builtin_fmaf(cub1(u), ZS, gv.y - M);
  float t2 = __builtin_fmaf(cub2(u), ZS, gv.z - M);
  float t3 = __builtin_fmaf(cub3(u), ZS, gv.w - M);
  return (ex2(t0) + ex2(t1)) + (ex2(t2) + ex2(t3));
}

// 16 columns for both rows of this wave
__device__ __forceinline__ void step16(uint4 za, uint4 zb, const float* gp,
                                       float M0, float M1, float& s0, float& s1){
  const float4 g0 = *(const float4*)(gp);
  const float4 g1 = *(const float4*)(gp + 4);
  const float4 g2 = *(const float4*)(gp + 8);
  const float4 g3 = *(const float4*)(gp + 12);
  s0 += (quad(za.x, g0, M0) + quad(za.y, g1, M0))
      + (quad(za.z, g2, M0) + quad(za.w, g3, M0));
  s1 += (quad(zb.x, g0, M1) + quad(zb.y, g1, M1))
      + (quad(zb.z, g2, M1) + quad(zb.w, g3, M1));
}

// ---------------------------------------------------------------------------
// prep: row sum-of-squares + bf16 copies + init gts = -y2*LOG2E - BIAS (g0=0)
// ---------------------------------------------------------------------------
__global__ __launch_bounds__(256) void prep_k(const float* __restrict__ x, const float* __restrict__ y,
                                              u16* __restrict__ xb, u16* __restrict__ yb,
                                              float* __restrict__ x2, float* __restrict__ y2,
                                              float* __restrict__ gts){
  const int w = threadIdx.x >> 6, l = threadIdx.x & 63;
  const int r = blockIdx.x * 4 + w;         // 0..16383
  const bool isx = r < N;
  const int rr = isx ? r : r - N;
  const float* src = (isx ? x : y) + (size_t)rr * DK;
  float4 v = *(const float4*)(src + l * 4);
  ushort4 bv;
  bv.x = f2bf(v.x); bv.y = f2bf(v.y); bv.z = f2bf(v.z); bv.w = f2bf(v.w);
  *(ushort4*)((isx ? xb : yb) + (size_t)rr * DK + l * 4) = bv;
  float p = v.x*v.x + v.y*v.y + v.z*v.z + v.w*v.w;
  #pragma unroll
  for (int off = 32; off > 0; off >>= 1) p += __shfl_down(p, off);
  if (l == 0){
    if (isx) x2[rr] = p;
    else { y2[rr] = p; gts[rr] = -p * LOG2E - BIAS; }
  }
}

// ---------------------------------------------------------------------------
// gemm: z = xb*yb^T (bf16 MFMA). Quantize Zl = 2*log2e*z to biased uint8,
// stage tiles in LDS, store zq and zqT coalesced dwordx4.
// ---------------------------------------------------------------------------
__global__ __launch_bounds__(256) void gemm_k(const u16* __restrict__ xb, const u16* __restrict__ yb,
                                              unsigned char* __restrict__ zq,
                                              unsigned char* __restrict__ zqT){
  __shared__ __align__(16) u16 As[128 * 72];
  __shared__ __align__(16) u16 Bs[128 * 72];
  const int t = threadIdx.x;
  const int w = t >> 6, l = t & 63;
  const int wm = w >> 1, wn = w & 1;
  const int brow = blockIdx.y * 128, bcol = blockIdx.x * 128;
  const int tr = t >> 3, tc = t & 7;
  f32x4 acc[4][4] = {};
  for (int ks = 0; ks < 4; ++ks){
    #pragma unroll
    for (int rr = 0; rr < 4; ++rr){
      const int row = tr + rr * 32;
      *(ushort8*)&As[row * 72 + tc * 8] = *(const ushort8*)&xb[(size_t)(brow + row) * DK + ks * 64 + tc * 8];
      *(ushort8*)&Bs[row * 72 + tc * 8] = *(const ushort8*)&yb[(size_t)(bcol + row) * DK + ks * 64 + tc * 8];
    }
    __syncthreads();
    #pragma unroll
    for (int kk = 0; kk < 2; ++kk){
      bf16x8 av[4], bv[4];
      #pragma unroll
      for (int mi = 0; mi < 4; ++mi){
        const int ar = wm * 64 + mi * 16 + (l & 15);
        av[mi] = __builtin_bit_cast(bf16x8, *(const ushort8*)&As[ar * 72 + kk * 32 + (l >> 4) * 8]);
      }
      #pragma unroll
      for (int ni = 0; ni < 4; ++ni){
        const int br = wn * 64 + ni * 16 + (l & 15);
        bv[ni] = __builtin_bit_cast(bf16x8, *(const ushort8*)&Bs[br * 72 + kk * 32 + (l >> 4) * 8]);
      }
      #pragma unroll
      for (int mi = 0; mi < 4; ++mi)
        #pragma unroll
        for (int ni = 0; ni < 4; ++ni)
          acc[mi][ni] = __builtin_amdgcn_mfma_f32_16x16x32_bf16(av[mi], bv[ni], acc[mi][ni], 0, 0, 0);
    }
    __syncthreads();
  }
  // quantize: Cs row-major [128][128]; Ct col-major [col][row] stride 144
  unsigned char* Cs = (unsigned char*)As;
  unsigned char* Ct = (unsigned char*)Bs;
  #pragma unroll
  for (int mi = 0; mi < 4; ++mi){
    const int rowb = wm * 64 + mi * 16 + (l >> 4) * 4;
    #pragma unroll
    for (int ni = 0; ni < 4; ++ni){
      const int col = wn * 64 + ni * 16 + (l & 15);
      unsigned pk = 0;
      #pragma unroll
      for (int rr = 0; rr < 4; ++rr){
        float q = fminf(fmaxf(acc[mi][ni][rr] * QS, -127.f), 127.f);
        unsigned b = (unsigned)((int)__builtin_rintf(q) + 128) & 255u;
        Cs[(rowb + rr) * 128 + col] = (unsigned char)b;
        pk |= b << (8 * rr);
      }
      *(unsigned*)(Ct + col * 144 + rowb) = pk;
    }
  }
  __syncthreads();
  const int trow0 = t >> 3, kseg = t & 7;
  #pragma unroll
  for (int ii = 0; ii < 4; ++ii){
    const int row = trow0 + ii * 32;
    int4 v = *(const int4*)(Cs + row * 128 + kseg * 16);
    *(int4*)(zq + (size_t)(brow + row) * N + bcol + kseg * 16) = v;
    int4 vt = *(const int4*)(Ct + row * 144 + kseg * 16);
    *(int4*)(zqT + (size_t)(bcol + row) * N + brow + kseg * 16) = vt;
  }
}

// ---------------------------------------------------------------------------
// sweept: bootstrap sweep with full online-max tracking (1 row/wave).
// Also stores pmax_out[i] = lse2 for the premax (fast) kernel.
// ---------------------------------------------------------------------------
__global__ __launch_bounds__(256) void sweept_k(const unsigned char* __restrict__ z,
                                                const float* __restrict__ din,
                                                float* __restrict__ dout,
                                                float* __restrict__ pmax_out){
  const int w = threadIdx.x >> 6, l = threadIdx.x & 63;
  const int i = blockIdx.x * 4 + w;
  const unsigned char* zr = z + (size_t)i * N + l * 16;
  float m = -1e30f, s = 0.f;
  uint4 zA = *(const uint4*)(zr);
  #pragma unroll
  for (int it = 0; it < 8; ++it){
    uint4 zB = zA;
    if (it < 7) zB = *(const uint4*)(zr + (it + 1) * 1024);
    const float* gp = din + it * 1024 + l * 16;
    const float4 g0 = *(const float4*)(gp);
    const float4 g1 = *(const float4*)(gp + 4);
    const float4 g2 = *(const float4*)(gp + 8);
    const float4 g3 = *(const float4*)(gp + 12);
    float tt[16];
    tt[0]  = __builtin_fmaf(cub0(zA.x), ZS, g0.x);
    tt[1]  = __builtin_fmaf(cub1(zA.x), ZS, g0.y);
    tt[2]  = __builtin_fmaf(cub2(zA.x), ZS, g0.z);
    tt[3]  = __builtin_fmaf(cub3(zA.x), ZS, g0.w);
    tt[4]  = __builtin_fmaf(cub0(zA.y), ZS, g1.x);
    tt[5]  = __builtin_fmaf(cub1(zA.y), ZS, g1.y);
    tt[6]  = __builtin_fmaf(cub2(zA.y), ZS, g1.z);
    tt[7]  = __builtin_fmaf(cub3(zA.y), ZS, g1.w);
    tt[8]  = __builtin_fmaf(cub0(zA.z), ZS, g2.x);
    tt[9]  = __builtin_fmaf(cub1(zA.z), ZS, g2.y);
    tt[10] = __builtin_fmaf(cub2(zA.z), ZS, g2.z);
    tt[11] = __builtin_fmaf(cub3(zA.z), ZS, g2.w);
    tt[12] = __builtin_fmaf(cub0(zA.w), ZS, g3.x);
    tt[13] = __builtin_fmaf(cub1(zA.w), ZS, g3.y);
    tt[14] = __builtin_fmaf(cub2(zA.w), ZS, g3.z);
    tt[15] = __builtin_fmaf(cub3(zA.w), ZS, g3.w);
    float a0 = fmaxf(tt[0], tt[1]),  a1 = fmaxf(tt[2], tt[3]);
    float a2 = fmaxf(tt[4], tt[5]),  a3 = fmaxf(tt[6], tt[7]);
    float a4 = fmaxf(tt[8], tt[9]),  a5 = fmaxf(tt[10], tt[11]);
    float a6 = fmaxf(tt[12], tt[13]), a7 = fmaxf(tt[14], tt[15]);
    float b0 = fmaxf(a0, a1), b1 = fmaxf(a2, a3), b2 = fmaxf(a4, a5), b3 = fmaxf(a6, a7);
    float nm = fmaxf(fmaxf(fmaxf(b0, b1), fmaxf(b2, b3)), m);
    float s0 = ex2(tt[0] - nm) + ex2(tt[1] - nm) + ex2(tt[2] - nm) + ex2(tt[3] - nm)
             + ex2(tt[4] - nm) + ex2(tt[5] - nm) + ex2(tt[6] - nm) + ex2(tt[7] - nm);
    float s1 = ex2(tt[8] - nm) + ex2(tt[9] - nm) + ex2(tt[10] - nm) + ex2(tt[11] - nm)
             + ex2(tt[12] - nm) + ex2(tt[13] - nm) + ex2(tt[14] - nm) + ex2(tt[15] - nm);
    s = __builtin_fmaf(s, ex2(m - nm), s0 + s1);
    m = nm;
    zA = zB;
  }
  #pragma unroll
  for (int off = 32; off > 0; off >>= 1){
    float om = __shfl_down(m, off);
    float os = __shfl_down(s, off);
    float nm = fmaxf(m, om);
    s = __builtin_fmaf(s, ex2(m - nm), os * ex2(om - nm));
    m = nm;
  }
  if (l == 0){
    float lse2 = m + lg2(s);          // true lse2 (bias cancels)
    dout[i] = 13.0f - lse2 - BIAS;
    pmax_out[i] = lse2;
  }
}

// ---------------------------------------------------------------------------
// sweepf: premax sweep. 2 rows/wave, half-row each; all 8 z-loads issued
// BEFORE compute (deep prefetch for L3/HBM latency). s = sum 2^(t - M),
// M = previous sweep's lse for the row (exact math, no max tracking).
// Block = 4 waves covers 4 rows x full width; LDS merge of the 2 halves.
// MODE 0: dout[i] = 13 - lse - BIAS ; pmax_out[i] = lse
// MODE 1: r_i = 2^(fprev_true + lse - 26); contrib = (fprev_true*ln2 + x2)*r
// ---------------------------------------------------------------------------
template<int MODE>
__global__ __launch_bounds__(256, 6) void sweepf_k(const unsigned char* __restrict__ z,
                                                   const float* __restrict__ din,
                                                   float* __restrict__ dout,
                                                   const float* __restrict__ pmax_in,
                                                   float* __restrict__ pmax_out,
                                                   const float* __restrict__ fprev,
                                                   const float* __restrict__ x2,
                                                   float* __restrict__ contrib){
  const int w = threadIdx.x >> 6, l = threadIdx.x & 63;
  const int p = w & 1, h = w >> 1;
  const int r0 = blockIdx.x * 4;
  const int i0 = r0 + 2 * p, i1 = i0 + 1;
  const int cbase = h * 4096 + l * 16;
  const unsigned char* z0 = z + (size_t)i0 * N + cbase;
  const unsigned char* z1 = z + (size_t)i1 * N + cbase;
  // issue ALL z loads up front (128 B in flight per wave)
  const uint4 a0 = *(const uint4*)(z0);
  const uint4 a1 = *(const uint4*)(z0 + 1024);
  const uint4 a2 = *(const uint4*)(z0 + 2048);
  const uint4 a3 = *(const uint4*)(z0 + 3072);
  const uint4 b0 = *(const uint4*)(z1);
  const uint4 b1 = *(const uint4*)(z1 + 1024);
  const uint4 b2 = *(const uint4*)(z1 + 2048);
  const uint4 b3 = *(const uint4*)(z1 + 3072);
  const float M0 = pmax_in[i0], M1 = pmax_in[i1];
  const float* gp = din + cbase;
  float s0 = 0.f, s1 = 0.f;
  step16(a0, b0, gp,        M0, M1, s0, s1);
  step16(a1, b1, gp + 1024, M0, M1, s0, s1);
  step16(a2, b2, gp + 2048, M0, M1, s0, s1);
  step16(a3, b3, gp + 3072, M0, M1, s0, s1);
  #pragma unroll
  for (int off = 32; off > 0; off >>= 1){
    s0 += __shfl_down(s0, off);
    s1 += __shfl_down(s1, off);
  }
  __shared__ float sB[4][2];
  if (l == 0){ sB[2 * p + 0][h] = s0; sB[2 * p + 1][h] = s1; }
  __syncthreads();
  if (threadIdx.x < 4){
    const int row = r0 + threadIdx.x;
    float s = sB[threadIdx.x][0] + sB[threadIdx.x][1];
    float M = pmax_in[row];
    float lse = M + lg2(s);
    if (MODE == 0){
      dout[row] = 13.0f - lse - BIAS;
      pmax_out[row] = lse;
    } else {
      float fti = fprev[row] + BIAS;    // true FtL
      float r = ex2(fti + lse - 26.0f);
      contrib[row] = (fti * LN2 + x2[row]) * r;
    }
  }
}

// ---------------------------------------------------------------------------
// finish: value = sum(contrib) + mean_j((gts_j+BIAS)*ln2 + y2_j); out = sqrt
// ---------------------------------------------------------------------------
__global__ __launch_bounds__(256) void finish_k(const float* __restrict__ contrib,
                                                const float* __restrict__ gts,
                                                const float* __restrict__ y2,
                                                float* __restrict__ out){
  __shared__ float s1[256], s2[256];
  const int t = threadIdx.x;
  float a = 0.f, b = 0.f;
  for (int j = t; j < N; j += 256){ a += contrib[j]; b += (gts[j] + BIAS) * LN2 + y2[j]; }
  s1[t] = a; s2[t] = b; __syncthreads();
  for (int st = 128; st > 0; st >>= 1){
    if (t < st){ s1[t] += s1[t + st]; s2[t] += s2[t + st]; }
    __syncthreads();
  }
  if (t == 0) out[0] = sqrtf(s1[0] + s2[0] * (1.0f / (float)N));
}

// ---------------------------------------------------------------------------
extern "C" void kernel_launch(void* const* d_in, const int* in_sizes, int n_in,
                              void* d_out, int out_size, void* d_ws, size_t ws_size,
                              hipStream_t stream){
  const float* x = (const float*)d_in[0];
  const float* y = (const float*)d_in[1];
  float* out = (float*)d_out;
  char* ws = (char*)d_ws;

  // workspace layout (bytes)
  unsigned char* zq  = (unsigned char*)(ws);              // 64 MiB
  unsigned char* zqT = (unsigned char*)(ws + 67108864);   // 64 MiB
  u16*   xb      = (u16*)  (ws + 134217728);              // 4 MiB
  u16*   yb      = (u16*)  (ws + 138412032);              // 4 MiB
  float* x2      = (float*)(ws + 142606336);
  float* y2      = (float*)(ws + 142639104);
  float* fts     = (float*)(ws + 142671872);
  float* gts     = (float*)(ws + 142704640);
  float* contrib = (float*)(ws + 142737408);
  float* pmaxF   = (float*)(ws + 142770176);
  float* pmaxG   = (float*)(ws + 142802944);

  prep_k<<<4096, 256, 0, stream>>>(x, y, xb, yb, x2, y2, gts);
  gemm_k<<<dim3(64, 64), 256, 0, stream>>>(xb, yb, zq, zqT);
  // bootstrap: 2 iterations with full max tracking (also seeds premax)
  for (int it = 0; it < 2; ++it){
    sweept_k<<<2048, 256, 0, stream>>>(zq,  gts, fts, pmaxF);
    sweept_k<<<2048, 256, 0, stream>>>(zqT, fts, gts, pmaxG);
  }
  // fast premax iterations
  for (int it = 2; it < 50; ++it){
    sweepf_k<0><<<2048, 256, 0, stream>>>(zq,  gts, fts, pmaxF, pmaxF, nullptr, nullptr, nullptr);
    sweepf_k<0><<<2048, 256, 0, stream>>>(zqT, fts, gts, pmaxG, pmaxG, nullptr, nullptr, nullptr);
  }
  sweepf_k<1><<<2048, 256, 0, stream>>>(zq, gts, nullptr, pmaxF, nullptr, fts, x2, contrib);
  finish_k<<<1, 256, 0, stream>>>(contrib, gts, y2, out);
}